// Round 1
// 1041.256 us; speedup vs baseline: 1.0020x; 1.0020x over previous
//
#include <hip/hip_runtime.h>
#include <stdint.h>

typedef __attribute__((ext_vector_type(8))) short bf16x8;
typedef __attribute__((ext_vector_type(4))) float f32x4;

#define D_MODEL 1024
#define SEQ 1024
#define NH 16
#define DK 64

__device__ __forceinline__ uint16_t f2bf(float f){
  uint32_t u = __float_as_uint(f);
  u += 0x7FFFu + ((u >> 16) & 1u);
  return (uint16_t)(u >> 16);
}
__device__ __forceinline__ f32x4 mfma16(bf16x8 a, bf16x8 b, f32x4 c){
  return __builtin_amdgcn_mfma_f32_16x16x32_bf16(a, b, c, 0, 0, 0);
}
__device__ __forceinline__ f32x4 f4zero(){
  f32x4 z = {0.f, 0.f, 0.f, 0.f};
  return z;
}
// async global->LDS, 16B per lane. LDS dest is wave-uniform base; HW adds lane*16.
__device__ __forceinline__ void gload_lds16(const uint16_t* g, void* l){
  __builtin_amdgcn_global_load_lds(
      (const __attribute__((address_space(1))) void*)g,
      (__attribute__((address_space(3))) void*)l,
      16, 0, 0);
}

// fp32 -> bf16 cast, vectorized (n4 = n/4)
__global__ __launch_bounds__(256) void cast_f32_bf16(const float* __restrict__ src,
                                                     uint16_t* __restrict__ dst, int n4){
  int i = blockIdx.x * blockDim.x + threadIdx.x;
  const int stride = gridDim.x * blockDim.x;
  for (; i < n4; i += stride){
    const float4 f = ((const float4*)src)[i];
    ushort4 o;
    o.x = f2bf(f.x); o.y = f2bf(f.y); o.z = f2bf(f.z); o.w = f2bf(f.w);
    ((ushort4*)dst)[i] = o;
  }
}

// C[M x 1024] = A[M x 1024] @ W[1024 x 1024]^T + bias (torch Linear). A,W bf16; bias fp32.
// m97 structure: 128x128 tile, BK=32, global_load_lds width=16, linear LDS [128][32].
// grid = (8, M/128), block = 256 (4 waves, 2x2 of 64x64/wave)
template<typename TO>
__global__ __launch_bounds__(256) void gemm_bt(const uint16_t* __restrict__ A,
                                               const uint16_t* __restrict__ W,
                                               const float* __restrict__ bias,
                                               TO* __restrict__ C){
  __shared__ __align__(16) uint16_t As[128 * 32];   // 8 KB
  __shared__ __align__(16) uint16_t Bs[128 * 32];   // 8 KB
  const int tid  = threadIdx.x;
  const int wave = tid >> 6;
  const int lane = tid & 63;
  const int l16  = lane & 15;
  const int quad = lane >> 4;
  const int bn = blockIdx.x, bm = blockIdx.y;
  const int wr = (wave >> 1) * 64;
  const int wc = (wave & 1) * 64;

  f32x4 acc[4][4];
  #pragma unroll
  for (int i = 0; i < 4; ++i){
    #pragma unroll
    for (int j = 0; j < 4; ++j) acc[i][j] = f4zero();
  }

  // Staging map (linear LDS): thread t <-> LDS byte t*16 <-> row t/4, u16-col (t%4)*8.
  // Issue i in {0,1} covers rows i*64 .. i*64+63.
  const int srow = tid >> 2;          // 0..63
  const int scol = (tid & 3) * 8;     // 0,8,16,24
  const uint16_t* Ag0 = A + (size_t)(bm * 128 + srow) * D_MODEL + scol;
  const uint16_t* Ag1 = Ag0 + (size_t)64 * D_MODEL;
  const uint16_t* Wg0 = W + (size_t)(bn * 128 + srow) * D_MODEL + scol;
  const uint16_t* Wg1 = Wg0 + (size_t)64 * D_MODEL;
  char* AsB = (char*)As + wave * 1024;   // wave-uniform LDS base, issue 0
  char* BsB = (char*)Bs + wave * 1024;

  for (int k0 = 0; k0 < D_MODEL; k0 += 32){
    __syncthreads();                       // previous iteration's LDS reads done
    gload_lds16(Ag0 + k0, AsB);
    gload_lds16(Ag1 + k0, AsB + 4096);
    gload_lds16(Wg0 + k0, BsB);
    gload_lds16(Wg1 + k0, BsB + 4096);
    __syncthreads();                       // vmcnt(0) drain before barrier covers gload_lds
    bf16x8 af[4], bfr[4];
    #pragma unroll
    for (int rt = 0; rt < 4; ++rt)
      af[rt] = *(const bf16x8*)&As[(wr + rt * 16 + l16) * 32 + quad * 8];
    #pragma unroll
    for (int ct = 0; ct < 4; ++ct)
      bfr[ct] = *(const bf16x8*)&Bs[(wc + ct * 16 + l16) * 32 + quad * 8];
    #pragma unroll
    for (int rt = 0; rt < 4; ++rt){
      #pragma unroll
      for (int ct = 0; ct < 4; ++ct)
        acc[rt][ct] = mfma16(af[rt], bfr[ct], acc[rt][ct]);
    }
  }

  #pragma unroll
  for (int ct = 0; ct < 4; ++ct){
    const int col = bn * 128 + wc + ct * 16 + l16;
    const float bc = bias[col];
    #pragma unroll
    for (int rt = 0; rt < 4; ++rt){
      const int row0 = bm * 128 + wr + rt * 16 + quad * 4;
      #pragma unroll
      for (int r = 0; r < 4; ++r){
        const float v = acc[rt][ct][r] + bc;
        if constexpr (sizeof(TO) == 2)
          C[(size_t)(row0 + r) * D_MODEL + col] = (TO)f2bf(v);
        else
          C[(size_t)(row0 + r) * D_MODEL + col] = (TO)v;
      }
    }
  }
}

// One block per (q-tile of 64, head, batch). block = 256; wave w owns q rows [w*16, w*16+16)
__global__ __launch_bounds__(256) void attn(const uint16_t* __restrict__ Qp,
                                            const uint16_t* __restrict__ Kp,
                                            const uint16_t* __restrict__ Vp,
                                            float* __restrict__ att,
                                            uint16_t* __restrict__ ctx){
  __shared__ __align__(16) uint16_t Qs[64 * 72];
  __shared__ __align__(16) uint16_t Vt[64 * 56];
  __shared__ __align__(16) uint16_t Pw[4 * 16 * 56];
  const int tid  = threadIdx.x;
  const int wave = tid >> 6;
  const int lane = tid & 63;
  const int l16  = lane & 15;
  const int quad = lane >> 4;
  const int qt = blockIdx.x;
  const int h  = blockIdx.y;
  const int b  = blockIdx.z;

  {
    const int r = tid >> 2;
    const int c = (tid & 3) * 16;
    const uint16_t* src = Qp + (size_t)(b * SEQ + qt * 64 + r) * D_MODEL + h * DK + c;
    const uint4 v0 = *(const uint4*)(src);
    const uint4 v1 = *(const uint4*)(src + 8);
    *(uint4*)&Qs[r * 72 + c]     = v0;
    *(uint4*)&Qs[r * 72 + c + 8] = v1;
  }
  __syncthreads();

  const bf16x8 aq0 = *(const bf16x8*)&Qs[(wave * 16 + l16) * 72 + quad * 8];
  const bf16x8 aq1 = *(const bf16x8*)&Qs[(wave * 16 + l16) * 72 + 32 + quad * 8];

  const uint16_t* Kb = Kp + (size_t)b * SEQ * D_MODEL + h * DK;

  // Pass 1: row sums of exp(s). |s| <= ~6 so fp32 exp is safe without max-subtract
  float lr[4] = {0.f, 0.f, 0.f, 0.f};
  for (int kt = 0; kt < 64; ++kt){
    const uint16_t* krow = Kb + (size_t)(kt * 16 + l16) * D_MODEL;
    const bf16x8 bk0 = *(const bf16x8*)(krow + quad * 8);
    const bf16x8 bk1 = *(const bf16x8*)(krow + 32 + quad * 8);
    f32x4 c = f4zero();
    c = mfma16(aq0, bk0, c);
    c = mfma16(aq1, bk1, c);
    #pragma unroll
    for (int r = 0; r < 4; ++r)
      lr[r] += __expf(c[r] * 0.125f);
  }
  for (int off = 1; off < 16; off <<= 1){
    #pragma unroll
    for (int r = 0; r < 4; ++r)
      lr[r] += __shfl_xor(lr[r], off);
  }
  float il[4];
  #pragma unroll
  for (int r = 0; r < 4; ++r) il[r] = 1.f / lr[r];

  f32x4 o[4];
  #pragma unroll
  for (int nt = 0; nt < 4; ++nt) o[nt] = f4zero();

  const int qrow0 = qt * 64 + wave * 16 + quad * 4;
  float* attw = att + (size_t)(b * NH + h) * SEQ * SEQ;

  // Pass 2: recompute scores -> probs (fp32 att out) + PV accumulate in 32-key chunks
  for (int kc = 0; kc < 32; ++kc){
    __syncthreads();
    {
      const int vr = tid >> 3;
      const int vc = (tid & 7) * 8;
      const uint4 vv = *(const uint4*)(Vp + (size_t)(b * SEQ + kc * 32 + vr) * D_MODEL + h * DK + vc);
      union { uint4 u; uint16_t s[8]; } tv;
      tv.u = vv;
      #pragma unroll
      for (int j = 0; j < 8; ++j)
        Vt[(vc + j) * 56 + vr] = tv.s[j];
    }
    #pragma unroll
    for (int half = 0; half < 2; ++half){
      const int kt = kc * 2 + half;
      const uint16_t* krow = Kb + (size_t)(kt * 16 + l16) * D_MODEL;
      const bf16x8 bk0 = *(const bf16x8*)(krow + quad * 8);
      const bf16x8 bk1 = *(const bf16x8*)(krow + 32 + quad * 8);
      f32x4 c = f4zero();
      c = mfma16(aq0, bk0, c);
      c = mfma16(aq1, bk1, c);
      const int kcol = kt * 16 + l16;
      #pragma unroll
      for (int r = 0; r < 4; ++r){
        const float p = __expf(c[r] * 0.125f) * il[r];
        attw[(size_t)(qrow0 + r) * SEQ + kcol] = p;
        Pw[(wave * 16 + quad * 4 + r) * 56 + half * 16 + l16] = f2bf(p);
      }
    }
    __syncthreads();
    const bf16x8 ap = *(const bf16x8*)&Pw[(wave * 16 + l16) * 56 + quad * 8];
    #pragma unroll
    for (int nt = 0; nt < 4; ++nt){
      const bf16x8 bv = *(const bf16x8*)&Vt[(nt * 16 + l16) * 56 + quad * 8];
      o[nt] = mfma16(ap, bv, o[nt]);
    }
  }

  #pragma unroll
  for (int nt = 0; nt < 4; ++nt){
    #pragma unroll
    for (int r = 0; r < 4; ++r)
      ctx[(size_t)(b * SEQ + qrow0 + r) * D_MODEL + h * DK + nt * 16 + l16] = f2bf(o[nt][r]);
  }
}

extern "C" void kernel_launch(void* const* d_in, const int* in_sizes, int n_in,
                              void* d_out, int out_size, void* d_ws, size_t ws_size,
                              hipStream_t stream){
  const float* q  = (const float*)d_in[0];
  const float* k  = (const float*)d_in[1];
  const float* v  = (const float*)d_in[2];
  const float* Wq = (const float*)d_in[3];
  const float* bq = (const float*)d_in[4];
  const float* Wk = (const float*)d_in[5];
  const float* bk = (const float*)d_in[6];
  const float* Wv = (const float*)d_in[7];
  const float* bv = (const float*)d_in[8];
  const float* Wo = (const float*)d_in[9];
  const float* bo = (const float*)d_in[10];

  uint16_t* ws = (uint16_t*)d_ws;
  const size_t NEL = (size_t)8 * SEQ * D_MODEL;   // 8,388,608
  const size_t WEL = (size_t)D_MODEL * D_MODEL;   // 1,048,576
  uint16_t* qb  = ws;
  uint16_t* kb  = ws + NEL;
  uint16_t* vb  = ws + 2 * NEL;
  uint16_t* Wqb = ws + 3 * NEL;
  uint16_t* Wkb = Wqb + WEL;
  uint16_t* Wvb = Wqb + 2 * WEL;
  uint16_t* Wob = Wqb + 3 * WEL;
  uint16_t* Qp  = Wqb + 4 * WEL;
  uint16_t* Kp  = Qp + NEL;
  uint16_t* Vp  = Qp + 2 * NEL;
  uint16_t* Ctx = Qp + 3 * NEL;

  float* outp = (float*)d_out;          // [8,1024,1024] fp32
  float* attp = outp + NEL;             // [8,16,1024,1024] fp32

  dim3 blk(256, 1, 1);
  cast_f32_bf16<<<dim3(1024), blk, 0, stream>>>(q, qb, (int)(NEL / 4));
  cast_f32_bf16<<<dim3(1024), blk, 0, stream>>>(k, kb, (int)(NEL / 4));
  cast_f32_bf16<<<dim3(1024), blk, 0, stream>>>(v, vb, (int)(NEL / 4));
  cast_f32_bf16<<<dim3(256),  blk, 0, stream>>>(Wq, Wqb, (int)(WEL / 4));
  cast_f32_bf16<<<dim3(256),  blk, 0, stream>>>(Wk, Wkb, (int)(WEL / 4));
  cast_f32_bf16<<<dim3(256),  blk, 0, stream>>>(Wv, Wvb, (int)(WEL / 4));
  cast_f32_bf16<<<dim3(256),  blk, 0, stream>>>(Wo, Wob, (int)(WEL / 4));

  dim3 gg(8, 64, 1);
  gemm_bt<uint16_t><<<gg, blk, 0, stream>>>(qb, Wqb, bq, Qp);
  gemm_bt<uint16_t><<<gg, blk, 0, stream>>>(kb, Wkb, bk, Kp);
  gemm_bt<uint16_t><<<gg, blk, 0, stream>>>(vb, Wvb, bv, Vp);
  attn<<<dim3(16, 16, 8), blk, 0, stream>>>(Qp, Kp, Vp, attp, Ctx);
  gemm_bt<float><<<gg, blk, 0, stream>>>(Ctx, Wob, bo, outp);
}